// Round 1
// baseline (366.804 us; speedup 1.0000x reference)
//
#include <hip/hip_runtime.h>
#include <hip/hip_bf16.h>
#include <math.h>

using bf16 = __hip_bfloat16;

typedef __attribute__((ext_vector_type(4))) float fv4;
typedef __attribute__((ext_vector_type(4))) short sh4;
typedef __attribute__((ext_vector_type(8))) short sh8;
typedef __attribute__((ext_vector_type(4))) float f4acc;

#define T_TOK 2048
#define HD    1024
#define NE    16
#define KD    1024
#define NPAIR 8192

// ---- workspace layout (bytes) ----
static constexpr size_t OFF_XB    = 0;                       // bf16 x  [2048][1024]   4 MiB
static constexpr size_t OFF_GU    = 4194304;                 // f32 gu  [2048][2048]  16 MiB
static constexpr size_t OFF_ACT   = 20971520;                // bf16 act[2048][1024]   4 MiB
static constexpr size_t OFF_H1    = 25165824;                // bf16 h1 [8192][1024]  16 MiB
static constexpr size_t OFF_Y     = 41943040;                // f32 y   [8192][1024]  32 MiB
static constexpr size_t OFF_TOPI  = 75497472;                // int  [2048*4]
static constexpr size_t OFF_TOPV  = 75530240;                // f32  [2048*4]
static constexpr size_t OFF_PTOK  = 75563008;                // int  [8192]
static constexpr size_t OFF_PSLOT = 75595776;                // int  [8192]
static constexpr size_t OFF_CNT   = 75628544;                // int  [16] (256B pad)
static constexpr size_t OFF_FILL  = 75628800;                // int  [16] (256B pad)
static constexpr size_t OFF_OFFS  = 75629056;                // int  [17]

__device__ __forceinline__ short f2bf(float f) {
  __hip_bfloat16 h = __float2bfloat16(f);
  union { __hip_bfloat16 b; short s; } u; u.b = h; return u.s;
}
__device__ __forceinline__ float bf2f(short s) {
  union { unsigned u; float f; } c; c.u = ((unsigned)(unsigned short)s) << 16; return c.f;
}
__device__ __forceinline__ void async16(const void* g, void* l) {
  __builtin_amdgcn_global_load_lds(
      (const __attribute__((address_space(1))) void*)g,
      (__attribute__((address_space(3))) void*)l, 16, 0, 0);
}

// ---------- cast x (fp32 -> bf16) ----------
__global__ __launch_bounds__(256) void cast_x_kernel(const float* __restrict__ x,
                                                     bf16* __restrict__ xb) {
  int i = blockIdx.x * 256 + threadIdx.x;      // one float4 per thread; 524288 total
  fv4 v = *(const fv4*)(x + (size_t)i * 4);
  sh4 o; o[0]=f2bf(v[0]); o[1]=f2bf(v[1]); o[2]=f2bf(v[2]); o[3]=f2bf(v[3]);
  *(sh4*)((short*)xb + (size_t)i * 4) = o;
}

// ---------- router: fp32 logits, softmax-top4-renorm ----------
__global__ __launch_bounds__(64) void router_kernel(const float* __restrict__ x,
                                                    const float* __restrict__ gw,
                                                    int* __restrict__ topi,
                                                    float* __restrict__ topv,
                                                    int* __restrict__ counts) {
  int t = blockIdx.x;
  int lane = threadIdx.x;
  __shared__ float logits[NE];
  const float* xr = x + (size_t)t * HD;
  for (int e = 0; e < NE; ++e) {
    const float* g = gw + (size_t)e * HD;
    float p = 0.f;
    for (int h = lane; h < HD; h += 64) p += xr[h] * g[h];
    for (int off = 32; off > 0; off >>= 1) p += __shfl_down(p, off);
    if (lane == 0) logits[e] = p;
  }
  __syncthreads();
  if (lane == 0) {
    float l[NE];
    bool used[NE];
    for (int i = 0; i < NE; ++i) { l[i] = logits[i]; used[i] = false; }
    int   idx[4]; float lv[4];
    for (int k = 0; k < 4; ++k) {
      int best = -1; float bv = -1e30f;
      for (int i = 0; i < NE; ++i)
        if (!used[i] && l[i] > bv) { bv = l[i]; best = i; }
      used[best] = true; idx[k] = best; lv[k] = bv;
    }
    float m = lv[0];
    float s = 0.f;
    for (int k = 0; k < 4; ++k) s += expf(lv[k] - m);
    for (int k = 0; k < 4; ++k) {
      topi[t * 4 + k] = idx[k];
      topv[t * 4 + k] = expf(lv[k] - m) / s;
      atomicAdd(&counts[idx[k]], 1);
    }
  }
}

// ---------- scan counts -> offsets ----------
__global__ void scan_kernel(const int* __restrict__ counts, int* __restrict__ offsets) {
  if (threadIdx.x == 0 && blockIdx.x == 0) {
    int acc = 0;
    for (int e = 0; e < NE; ++e) { offsets[e] = acc; acc += counts[e]; }
    offsets[NE] = acc;
  }
}

// ---------- assign pair slots ----------
__global__ __launch_bounds__(256) void assign_kernel(const int* __restrict__ topi,
                                                     const int* __restrict__ offsets,
                                                     int* __restrict__ fill,
                                                     int* __restrict__ pair_token,
                                                     int* __restrict__ pair_slot) {
  int p = blockIdx.x * 256 + threadIdx.x;     // 8192
  if (p >= NPAIR) return;
  int t = p >> 2;
  int e = topi[p];
  int pos = atomicAdd(&fill[e], 1);
  int slot = offsets[e] + pos;
  pair_token[slot] = t;
  pair_slot[p] = slot;
}

// ---------- templated GEMM: C[M,N] = A_bf16[M,K] @ B_f32[N,K]^T ----------
// MODE 0: GU    A=x_bf16 M=2048, B=shared_gu N=2048 -> gu f32 (stride 2048)
// MODE 1: DOWN  A=act    M=2048, B=shared_down N=1024 -> d_out f32
// MODE 2: H1    A=x_bf16 gathered by pair_token, B=w1[e] -> silu -> h1 bf16
// MODE 3: YP    A=h1 rows=slots, B=w2[e] -> y f32
template <int MODE>
__global__ __launch_bounds__(256) void gemm_kernel(const bf16* __restrict__ Abase,
                                                   const float* __restrict__ Bbase,
                                                   void* __restrict__ OutBase,
                                                   const int* __restrict__ pair_token,
                                                   const int* __restrict__ offsets) {
  constexpr int NCOLS = (MODE == 0) ? 2048 : 1024;
  constexpr int NT = NCOLS / 128;

  __shared__ bf16 Ash[128][32];
  __shared__ bf16 Bsh[128][32];

  const int tid = threadIdx.x;
  const int lane = tid & 63;
  const int wave = tid >> 6;
  const int wm = wave >> 1, wn = wave & 1;

  int mt, nt, seg_start = 0, count = 0;
  size_t ebase = 0;
  if (MODE == 0 || MODE == 1) {
    mt = blockIdx.x / NT; nt = blockIdx.x % NT;
  } else {
    int e = blockIdx.x / (16 * NT);
    int r = blockIdx.x % (16 * NT);
    mt = r / NT; nt = r % NT;
    seg_start = offsets[e];
    count = offsets[e + 1] - seg_start;
    if (mt * 128 >= count) return;
    ebase = (size_t)e * 1024 * 1024;
  }

  // Precompute per-lane A row base pointers for the two staging rounds
  const bf16* arow[2];
#pragma unroll
  for (int r = 0; r < 2; ++r) {
    int rowloc = r * 64 + wave * 16 + (lane >> 2);
    int grow;
    if (MODE == 0 || MODE == 1) {
      grow = mt * 128 + rowloc;
    } else {
      int slot = seg_start + mt * 128 + rowloc;
      if (slot > NPAIR - 1) slot = NPAIR - 1;
      grow = (MODE == 2) ? pair_token[slot] : slot;
    }
    arow[r] = Abase + (size_t)grow * KD + (lane & 3) * 8;
  }

  const float* Bexp = Bbase + ebase + (size_t)(nt * 128) * KD;

  f4acc acc[4][4];
#pragma unroll
  for (int i = 0; i < 4; ++i)
#pragma unroll
    for (int j = 0; j < 4; ++j) acc[i][j] = (f4acc)(0.f);

  for (int kt = 0; kt < KD / 32; ++kt) {
    const int k0 = kt * 32;
    // stage A tile via global_load_lds (each wave: 16 rows per round)
#pragma unroll
    for (int r = 0; r < 2; ++r) {
      async16(arow[r] + k0, (void*)&Ash[r * 64 + wave * 16][0]);
    }
    // stage B tile: fp32 -> bf16 reg-staged
#pragma unroll
    for (int r = 0; r < 4; ++r) {
      int idx = (r << 8) + tid;
      int row = idx >> 3, cg = idx & 7;
      fv4 v = *(const fv4*)(Bexp + (size_t)row * KD + k0 + (cg << 2));
      sh4 pk; pk[0]=f2bf(v[0]); pk[1]=f2bf(v[1]); pk[2]=f2bf(v[2]); pk[3]=f2bf(v[3]);
      *(sh4*)&Bsh[row][cg << 2] = pk;
    }
    __syncthreads();

    sh8 fa[4], fb[4];
#pragma unroll
    for (int mi = 0; mi < 4; ++mi)
      fa[mi] = *(const sh8*)&Ash[wm * 64 + mi * 16 + (lane & 15)][(lane >> 4) * 8];
#pragma unroll
    for (int ni = 0; ni < 4; ++ni)
      fb[ni] = *(const sh8*)&Bsh[wn * 64 + ni * 16 + (lane & 15)][(lane >> 4) * 8];
#pragma unroll
    for (int mi = 0; mi < 4; ++mi)
#pragma unroll
      for (int ni = 0; ni < 4; ++ni)
        acc[mi][ni] = __builtin_amdgcn_mfma_f32_16x16x32_bf16(fa[mi], fb[ni], acc[mi][ni], 0, 0, 0);
    __syncthreads();
  }

  // epilogue: C/D layout col = lane&15, row = (lane>>4)*4 + j
#pragma unroll
  for (int mi = 0; mi < 4; ++mi) {
#pragma unroll
    for (int ni = 0; ni < 4; ++ni) {
#pragma unroll
      for (int j = 0; j < 4; ++j) {
        int rloc = wm * 64 + mi * 16 + (lane >> 4) * 4 + j;
        int cloc = wn * 64 + ni * 16 + (lane & 15);
        float v = acc[mi][ni][j];
        if (MODE == 0) {
          ((float*)OutBase)[(size_t)(mt * 128 + rloc) * 2048 + nt * 128 + cloc] = v;
        } else if (MODE == 1) {
          ((float*)OutBase)[(size_t)(mt * 128 + rloc) * 1024 + nt * 128 + cloc] = v;
        } else if (MODE == 2) {
          if (mt * 128 + rloc < count) {
            float s = v / (1.f + expf(-v));
            ((short*)OutBase)[(size_t)(seg_start + mt * 128 + rloc) * 1024 + nt * 128 + cloc] = f2bf(s);
          }
        } else {
          if (mt * 128 + rloc < count)
            ((float*)OutBase)[(size_t)(seg_start + mt * 128 + rloc) * 1024 + nt * 128 + cloc] = v;
        }
      }
    }
  }
}

// ---------- shared-expert activation: act = silu(gate) * up ----------
__global__ __launch_bounds__(256) void act_kernel(const float* __restrict__ gu,
                                                  bf16* __restrict__ act) {
  int i = blockIdx.x * 256 + threadIdx.x;  // 2048*256; 4 elems each
  int t = i >> 8, g = i & 255;
  fv4 gate = *(const fv4*)(gu + (size_t)t * 2048 + g * 4);
  fv4 up   = *(const fv4*)(gu + (size_t)t * 2048 + 1024 + g * 4);
  sh4 o;
#pragma unroll
  for (int q = 0; q < 4; ++q) {
    float gg = gate[q];
    float s = gg / (1.f + expf(-gg)) * up[q];
    o[q] = f2bf(s);
  }
  *(sh4*)((short*)act + (size_t)t * 1024 + g * 4) = o;
}

// ---------- final: out += sum_k w_k * y[slot_k] ----------
__global__ __launch_bounds__(256) void reduce_kernel(float* __restrict__ out,
                                                     const float* __restrict__ y,
                                                     const int* __restrict__ pslot,
                                                     const float* __restrict__ topv) {
  int t = blockIdx.x;
  int q = threadIdx.x;  // 256 float4 per row
  int s0 = pslot[t * 4 + 0], s1 = pslot[t * 4 + 1];
  int s2 = pslot[t * 4 + 2], s3 = pslot[t * 4 + 3];
  float w0 = topv[t * 4 + 0], w1 = topv[t * 4 + 1];
  float w2 = topv[t * 4 + 2], w3 = topv[t * 4 + 3];
  fv4 o = ((const fv4*)(out + (size_t)t * 1024))[q];
  o += w0 * ((const fv4*)(y + (size_t)s0 * 1024))[q];
  o += w1 * ((const fv4*)(y + (size_t)s1 * 1024))[q];
  o += w2 * ((const fv4*)(y + (size_t)s2 * 1024))[q];
  o += w3 * ((const fv4*)(y + (size_t)s3 * 1024))[q];
  ((fv4*)(out + (size_t)t * 1024))[q] = o;
}

extern "C" void kernel_launch(void* const* d_in, const int* in_sizes, int n_in,
                              void* d_out, int out_size, void* d_ws, size_t ws_size,
                              hipStream_t stream) {
  const float* x   = (const float*)d_in[0];
  const float* gw  = (const float*)d_in[1];
  const float* w1  = (const float*)d_in[2];
  const float* w2  = (const float*)d_in[3];
  const float* sgu = (const float*)d_in[4];
  const float* sdn = (const float*)d_in[5];
  float* out = (float*)d_out;

  char* ws = (char*)d_ws;
  bf16*  xb    = (bf16*)(ws + OFF_XB);
  float* gu    = (float*)(ws + OFF_GU);
  bf16*  act   = (bf16*)(ws + OFF_ACT);
  bf16*  h1    = (bf16*)(ws + OFF_H1);
  float* yb    = (float*)(ws + OFF_Y);
  int*   topi  = (int*)(ws + OFF_TOPI);
  float* topv  = (float*)(ws + OFF_TOPV);
  int*   ptok  = (int*)(ws + OFF_PTOK);
  int*   pslot = (int*)(ws + OFF_PSLOT);
  int*   cnt   = (int*)(ws + OFF_CNT);
  int*   fill  = (int*)(ws + OFF_FILL);
  int*   offs  = (int*)(ws + OFF_OFFS);

  hipMemsetAsync(ws + OFF_CNT, 0, 512, stream);  // counts + fill

  cast_x_kernel<<<2048, 256, 0, stream>>>(x, xb);
  router_kernel<<<2048, 64, 0, stream>>>(x, gw, topi, topv, cnt);
  scan_kernel<<<1, 64, 0, stream>>>(cnt, offs);
  assign_kernel<<<32, 256, 0, stream>>>(topi, offs, fill, ptok, pslot);

  // shared expert
  gemm_kernel<0><<<16 * 16, 256, 0, stream>>>(xb, sgu, gu, nullptr, nullptr);
  act_kernel<<<2048, 256, 0, stream>>>(gu, act);
  gemm_kernel<1><<<16 * 8, 256, 0, stream>>>(act, sdn, out, nullptr, nullptr);

  // routed experts
  gemm_kernel<2><<<16 * 16 * 8, 256, 0, stream>>>(xb, w1, h1, ptok, offs);
  gemm_kernel<3><<<16 * 16 * 8, 256, 0, stream>>>(h1, w2, yb, ptok, offs);

  reduce_kernel<<<2048, 256, 0, stream>>>(out, yb, pslot, topv);
}

// Round 2
// 310.711 us; speedup vs baseline: 1.1805x; 1.1805x over previous
//
#include <hip/hip_runtime.h>
#include <hip/hip_bf16.h>
#include <math.h>

using bf16 = __hip_bfloat16;

typedef __attribute__((ext_vector_type(4))) float fv4;
typedef __attribute__((ext_vector_type(4))) short sh4;
typedef __attribute__((ext_vector_type(8))) short sh8;
typedef __attribute__((ext_vector_type(4))) float f4acc;

#define T_TOK 2048
#define HD    1024
#define NE    16
#define KD    1024
#define NPAIR 8192

// ---- workspace layout (bytes) ----
static constexpr size_t OFF_XB    = 0;                       // bf16 x  [2048][1024]   4 MiB
static constexpr size_t OFF_GU    = 4194304;                 // f32 gu  [2048][2048]  16 MiB
static constexpr size_t OFF_ACT   = 20971520;                // bf16 act[2048][1024]   4 MiB
static constexpr size_t OFF_H1    = 25165824;                // bf16 h1 [8192][1024]  16 MiB
static constexpr size_t OFF_Y     = 41943040;                // f32 y   [8192][1024]  32 MiB
static constexpr size_t OFF_TOPI  = 75497472;                // int  [2048*4]
static constexpr size_t OFF_TOPV  = 75530240;                // f32  [2048*4]
static constexpr size_t OFF_PTOK  = 75563008;                // int  [8192]
static constexpr size_t OFF_PSLOT = 75595776;                // int  [8192]
static constexpr size_t OFF_CNT   = 75628544;                // int  [16] (256B pad)
static constexpr size_t OFF_FILL  = 75628800;                // int  [16] (256B pad)
static constexpr size_t OFF_OFFS  = 75629056;                // int  [17]

__device__ __forceinline__ short f2bf(float f) {
  __hip_bfloat16 h = __float2bfloat16(f);
  union { __hip_bfloat16 b; short s; } u; u.b = h; return u.s;
}
__device__ __forceinline__ float bf2f(short s) {
  union { unsigned u; float f; } c; c.u = ((unsigned)(unsigned short)s) << 16; return c.f;
}
__device__ __forceinline__ void async16(const void* g, void* l) {
  __builtin_amdgcn_global_load_lds(
      (const __attribute__((address_space(1))) void*)g,
      (__attribute__((address_space(3))) void*)l, 16, 0, 0);
}

// ---------- cast x (fp32 -> bf16) ----------
__global__ __launch_bounds__(256) void cast_x_kernel(const float* __restrict__ x,
                                                     bf16* __restrict__ xb) {
  int i = blockIdx.x * 256 + threadIdx.x;      // one float4 per thread; 524288 total
  fv4 v = *(const fv4*)(x + (size_t)i * 4);
  sh4 o; o[0]=f2bf(v[0]); o[1]=f2bf(v[1]); o[2]=f2bf(v[2]); o[3]=f2bf(v[3]);
  *(sh4*)((short*)xb + (size_t)i * 4) = o;
}

// ---------- router v2: wave-per-token, x register-resident, batched reduce ----------
__global__ __launch_bounds__(256) void router_kernel(const float* __restrict__ x,
                                                     const float* __restrict__ gw,
                                                     int* __restrict__ topi,
                                                     float* __restrict__ topv,
                                                     int* __restrict__ counts) {
  const int wave = threadIdx.x >> 6;
  const int lane = threadIdx.x & 63;
  const int t = blockIdx.x * 4 + wave;

  const float* xr = x + (size_t)t * HD;
  // x row register-resident: lane holds h = q*256 + lane*4 .. +3
  fv4 xa[4];
#pragma unroll
  for (int q = 0; q < 4; ++q) xa[q] = *(const fv4*)(xr + q * 256 + lane * 4);

  float p[NE];
#pragma unroll
  for (int e = 0; e < NE; ++e) {
    const float* g = gw + (size_t)e * HD;
    float a = 0.f;
#pragma unroll
    for (int q = 0; q < 4; ++q) {
      fv4 gv = *(const fv4*)(g + q * 256 + lane * 4);
      a += xa[q][0] * gv[0] + xa[q][1] * gv[1] + xa[q][2] * gv[2] + xa[q][3] * gv[3];
    }
    p[e] = a;
  }
  // batched butterfly reduction across 64 lanes for all 16 experts
#pragma unroll
  for (int off = 1; off < 64; off <<= 1) {
#pragma unroll
    for (int e = 0; e < NE; ++e) p[e] += __shfl_xor(p[e], off);
  }

  if (lane == 0) {
    bool used[NE];
#pragma unroll
    for (int i = 0; i < NE; ++i) used[i] = false;
    int idx[4]; float lv[4];
    for (int k = 0; k < 4; ++k) {
      int best = -1; float bv = -1e30f;
      for (int i = 0; i < NE; ++i)
        if (!used[i] && p[i] > bv) { bv = p[i]; best = i; }
      used[best] = true; idx[k] = best; lv[k] = bv;
    }
    float m = lv[0];
    float s = 0.f;
    for (int k = 0; k < 4; ++k) s += expf(lv[k] - m);
    for (int k = 0; k < 4; ++k) {
      topi[t * 4 + k] = idx[k];
      topv[t * 4 + k] = expf(lv[k] - m) / s;
      atomicAdd(&counts[idx[k]], 1);
    }
  }
}

// ---------- scan counts -> offsets ----------
__global__ void scan_kernel(const int* __restrict__ counts, int* __restrict__ offsets) {
  if (threadIdx.x == 0 && blockIdx.x == 0) {
    int acc = 0;
    for (int e = 0; e < NE; ++e) { offsets[e] = acc; acc += counts[e]; }
    offsets[NE] = acc;
  }
}

// ---------- assign pair slots ----------
__global__ __launch_bounds__(256) void assign_kernel(const int* __restrict__ topi,
                                                     const int* __restrict__ offsets,
                                                     int* __restrict__ fill,
                                                     int* __restrict__ pair_token,
                                                     int* __restrict__ pair_slot) {
  int p = blockIdx.x * 256 + threadIdx.x;     // 8192
  if (p >= NPAIR) return;
  int t = p >> 2;
  int e = topi[p];
  int pos = atomicAdd(&fill[e], 1);
  int slot = offsets[e] + pos;
  pair_token[slot] = t;
  pair_slot[p] = slot;
}

// ---------- templated GEMM: C[M,N] = A_bf16[M,K] @ B_f32[N,K]^T ----------
// MODE 0: GU    A=x_bf16 M=2048, B=shared_gu N=2048 -> gu f32 (stride 2048)
// MODE 1: DOWN  A=act    M=2048, B=shared_down N=1024 -> d_out f32
// MODE 2: H1    A=x_bf16 gathered by pair_token, B=w1[e] -> silu -> h1 bf16
// MODE 3: YP    A=h1 rows=slots, B=w2[e] -> y f32
template <int MODE>
__global__ __launch_bounds__(256) void gemm_kernel(const bf16* __restrict__ Abase,
                                                   const float* __restrict__ Bbase,
                                                   void* __restrict__ OutBase,
                                                   const int* __restrict__ pair_token,
                                                   const int* __restrict__ offsets) {
  constexpr int NCOLS = (MODE == 0) ? 2048 : 1024;
  constexpr int NT = NCOLS / 128;

  __shared__ bf16 Ash[128][32];
  __shared__ bf16 Bsh[128][32];

  const int tid = threadIdx.x;
  const int lane = tid & 63;
  const int wave = tid >> 6;
  const int wm = wave >> 1, wn = wave & 1;

  int mt, nt, seg_start = 0, count = 0;
  size_t ebase = 0;
  if (MODE == 0 || MODE == 1) {
    mt = blockIdx.x / NT; nt = blockIdx.x % NT;
  } else {
    int e = blockIdx.x / (16 * NT);
    int r = blockIdx.x % (16 * NT);
    mt = r / NT; nt = r % NT;
    seg_start = offsets[e];
    count = offsets[e + 1] - seg_start;
    if (mt * 128 >= count) return;
    ebase = (size_t)e * 1024 * 1024;
  }

  // Precompute per-lane A row base pointers for the two staging rounds
  const bf16* arow[2];
#pragma unroll
  for (int r = 0; r < 2; ++r) {
    int rowloc = r * 64 + wave * 16 + (lane >> 2);
    int grow;
    if (MODE == 0 || MODE == 1) {
      grow = mt * 128 + rowloc;
    } else {
      int slot = seg_start + mt * 128 + rowloc;
      if (slot > NPAIR - 1) slot = NPAIR - 1;
      grow = (MODE == 2) ? pair_token[slot] : slot;
    }
    arow[r] = Abase + (size_t)grow * KD + (lane & 3) * 8;
  }

  const float* Bexp = Bbase + ebase + (size_t)(nt * 128) * KD;

  f4acc acc[4][4];
#pragma unroll
  for (int i = 0; i < 4; ++i)
#pragma unroll
    for (int j = 0; j < 4; ++j) acc[i][j] = (f4acc)(0.f);

  for (int kt = 0; kt < KD / 32; ++kt) {
    const int k0 = kt * 32;
    // stage A tile via global_load_lds (each wave: 16 rows per round)
#pragma unroll
    for (int r = 0; r < 2; ++r) {
      async16(arow[r] + k0, (void*)&Ash[r * 64 + wave * 16][0]);
    }
    // stage B tile: fp32 -> bf16 reg-staged
#pragma unroll
    for (int r = 0; r < 4; ++r) {
      int idx = (r << 8) + tid;
      int row = idx >> 3, cg = idx & 7;
      fv4 v = *(const fv4*)(Bexp + (size_t)row * KD + k0 + (cg << 2));
      sh4 pk; pk[0]=f2bf(v[0]); pk[1]=f2bf(v[1]); pk[2]=f2bf(v[2]); pk[3]=f2bf(v[3]);
      *(sh4*)&Bsh[row][cg << 2] = pk;
    }
    __syncthreads();

    sh8 fa[4], fb[4];
#pragma unroll
    for (int mi = 0; mi < 4; ++mi)
      fa[mi] = *(const sh8*)&Ash[wm * 64 + mi * 16 + (lane & 15)][(lane >> 4) * 8];
#pragma unroll
    for (int ni = 0; ni < 4; ++ni)
      fb[ni] = *(const sh8*)&Bsh[wn * 64 + ni * 16 + (lane & 15)][(lane >> 4) * 8];
#pragma unroll
    for (int mi = 0; mi < 4; ++mi)
#pragma unroll
      for (int ni = 0; ni < 4; ++ni)
        acc[mi][ni] = __builtin_amdgcn_mfma_f32_16x16x32_bf16(fa[mi], fb[ni], acc[mi][ni], 0, 0, 0);
    __syncthreads();
  }

  // epilogue: C/D layout col = lane&15, row = (lane>>4)*4 + j
#pragma unroll
  for (int mi = 0; mi < 4; ++mi) {
#pragma unroll
    for (int ni = 0; ni < 4; ++ni) {
#pragma unroll
      for (int j = 0; j < 4; ++j) {
        int rloc = wm * 64 + mi * 16 + (lane >> 4) * 4 + j;
        int cloc = wn * 64 + ni * 16 + (lane & 15);
        float v = acc[mi][ni][j];
        if (MODE == 0) {
          ((float*)OutBase)[(size_t)(mt * 128 + rloc) * 2048 + nt * 128 + cloc] = v;
        } else if (MODE == 1) {
          ((float*)OutBase)[(size_t)(mt * 128 + rloc) * 1024 + nt * 128 + cloc] = v;
        } else if (MODE == 2) {
          if (mt * 128 + rloc < count) {
            float s = v / (1.f + expf(-v));
            ((short*)OutBase)[(size_t)(seg_start + mt * 128 + rloc) * 1024 + nt * 128 + cloc] = f2bf(s);
          }
        } else {
          if (mt * 128 + rloc < count)
            ((float*)OutBase)[(size_t)(seg_start + mt * 128 + rloc) * 1024 + nt * 128 + cloc] = v;
        }
      }
    }
  }
}

// ---------- shared-expert activation: act = silu(gate) * up ----------
__global__ __launch_bounds__(256) void act_kernel(const float* __restrict__ gu,
                                                  bf16* __restrict__ act) {
  int i = blockIdx.x * 256 + threadIdx.x;  // 2048*256; 4 elems each
  int t = i >> 8, g = i & 255;
  fv4 gate = *(const fv4*)(gu + (size_t)t * 2048 + g * 4);
  fv4 up   = *(const fv4*)(gu + (size_t)t * 2048 + 1024 + g * 4);
  sh4 o;
#pragma unroll
  for (int q = 0; q < 4; ++q) {
    float gg = gate[q];
    float s = gg / (1.f + expf(-gg)) * up[q];
    o[q] = f2bf(s);
  }
  *(sh4*)((short*)act + (size_t)t * 1024 + g * 4) = o;
}

// ---------- final: out += sum_k w_k * y[slot_k] ----------
__global__ __launch_bounds__(256) void reduce_kernel(float* __restrict__ out,
                                                     const float* __restrict__ y,
                                                     const int* __restrict__ pslot,
                                                     const float* __restrict__ topv) {
  int t = blockIdx.x;
  int q = threadIdx.x;  // 256 float4 per row
  int s0 = pslot[t * 4 + 0], s1 = pslot[t * 4 + 1];
  int s2 = pslot[t * 4 + 2], s3 = pslot[t * 4 + 3];
  float w0 = topv[t * 4 + 0], w1 = topv[t * 4 + 1];
  float w2 = topv[t * 4 + 2], w3 = topv[t * 4 + 3];
  fv4 o = ((const fv4*)(out + (size_t)t * 1024))[q];
  o += w0 * ((const fv4*)(y + (size_t)s0 * 1024))[q];
  o += w1 * ((const fv4*)(y + (size_t)s1 * 1024))[q];
  o += w2 * ((const fv4*)(y + (size_t)s2 * 1024))[q];
  o += w3 * ((const fv4*)(y + (size_t)s3 * 1024))[q];
  ((fv4*)(out + (size_t)t * 1024))[q] = o;
}

extern "C" void kernel_launch(void* const* d_in, const int* in_sizes, int n_in,
                              void* d_out, int out_size, void* d_ws, size_t ws_size,
                              hipStream_t stream) {
  const float* x   = (const float*)d_in[0];
  const float* gw  = (const float*)d_in[1];
  const float* w1  = (const float*)d_in[2];
  const float* w2  = (const float*)d_in[3];
  const float* sgu = (const float*)d_in[4];
  const float* sdn = (const float*)d_in[5];
  float* out = (float*)d_out;

  char* ws = (char*)d_ws;
  bf16*  xb    = (bf16*)(ws + OFF_XB);
  float* gu    = (float*)(ws + OFF_GU);
  bf16*  act   = (bf16*)(ws + OFF_ACT);
  bf16*  h1    = (bf16*)(ws + OFF_H1);
  float* yb    = (float*)(ws + OFF_Y);
  int*   topi  = (int*)(ws + OFF_TOPI);
  float* topv  = (float*)(ws + OFF_TOPV);
  int*   ptok  = (int*)(ws + OFF_PTOK);
  int*   pslot = (int*)(ws + OFF_PSLOT);
  int*   cnt   = (int*)(ws + OFF_CNT);
  int*   fill  = (int*)(ws + OFF_FILL);
  int*   offs  = (int*)(ws + OFF_OFFS);

  hipMemsetAsync(ws + OFF_CNT, 0, 512, stream);  // counts + fill

  cast_x_kernel<<<2048, 256, 0, stream>>>(x, xb);
  router_kernel<<<512, 256, 0, stream>>>(x, gw, topi, topv, cnt);
  scan_kernel<<<1, 64, 0, stream>>>(cnt, offs);
  assign_kernel<<<32, 256, 0, stream>>>(topi, offs, fill, ptok, pslot);

  // shared expert
  gemm_kernel<0><<<16 * 16, 256, 0, stream>>>(xb, sgu, gu, nullptr, nullptr);
  act_kernel<<<2048, 256, 0, stream>>>(gu, act);
  gemm_kernel<1><<<16 * 8, 256, 0, stream>>>(act, sdn, out, nullptr, nullptr);

  // routed experts
  gemm_kernel<2><<<16 * 16 * 8, 256, 0, stream>>>(xb, w1, h1, ptok, offs);
  gemm_kernel<3><<<16 * 16 * 8, 256, 0, stream>>>(h1, w2, yb, ptok, offs);

  reduce_kernel<<<2048, 256, 0, stream>>>(out, yb, pslot, topv);
}

// Round 3
// 305.297 us; speedup vs baseline: 1.2015x; 1.0177x over previous
//
#include <hip/hip_runtime.h>
#include <hip/hip_bf16.h>
#include <math.h>

using bf16 = __hip_bfloat16;

typedef __attribute__((ext_vector_type(4))) float fv4;
typedef __attribute__((ext_vector_type(4))) short sh4;
typedef __attribute__((ext_vector_type(8))) short sh8;
typedef __attribute__((ext_vector_type(4))) float f4acc;

#define T_TOK 2048
#define HD    1024
#define NE    16
#define KD    1024
#define NPAIR 8192

// ---- workspace layout (bytes) ----
static constexpr size_t OFF_XB    = 0;                       // bf16 x  [2048][1024]   4 MiB
static constexpr size_t OFF_GU    = 4194304;                 // f32 gu  [2048][2048]  16 MiB
static constexpr size_t OFF_ACT   = 20971520;                // bf16 act[2048][1024]   4 MiB
static constexpr size_t OFF_H1    = 25165824;                // bf16 h1 [8192][1024]  16 MiB
static constexpr size_t OFF_Y     = 41943040;                // f32 y   [8192][1024]  32 MiB
static constexpr size_t OFF_TOPI  = 75497472;                // int  [2048*4]
static constexpr size_t OFF_TOPV  = 75530240;                // f32  [2048*4]
static constexpr size_t OFF_PTOK  = 75563008;                // int  [8192]
static constexpr size_t OFF_PSLOT = 75595776;                // int  [8192]
static constexpr size_t OFF_CNT   = 75628544;                // int  [16] (256B pad)
static constexpr size_t OFF_FILL  = 75628800;                // int  [16] (256B pad)
static constexpr size_t OFF_OFFS  = 75629056;                // int  [17]

__device__ __forceinline__ short f2bf(float f) {
  __hip_bfloat16 h = __float2bfloat16(f);
  union { __hip_bfloat16 b; short s; } u; u.b = h; return u.s;
}
__device__ __forceinline__ float bf2f(short s) {
  union { unsigned u; float f; } c; c.u = ((unsigned)(unsigned short)s) << 16; return c.f;
}
__device__ __forceinline__ void async16(const void* g, void* l) {
  __builtin_amdgcn_global_load_lds(
      (const __attribute__((address_space(1))) void*)g,
      (__attribute__((address_space(3))) void*)l, 16, 0, 0);
}

// ---------- cast x (fp32 -> bf16) ----------
__global__ __launch_bounds__(256) void cast_x_kernel(const float* __restrict__ x,
                                                     bf16* __restrict__ xb) {
  int i = blockIdx.x * 256 + threadIdx.x;      // one float4 per thread; 524288 total
  fv4 v = *(const fv4*)(x + (size_t)i * 4);
  sh4 o; o[0]=f2bf(v[0]); o[1]=f2bf(v[1]); o[2]=f2bf(v[2]); o[3]=f2bf(v[3]);
  *(sh4*)((short*)xb + (size_t)i * 4) = o;
}

// ---------- router v3: gw in LDS, branchless register top-4, no scratch ----------
__global__ __launch_bounds__(256) void router_kernel(const float* __restrict__ x,
                                                     const float* __restrict__ gw,
                                                     int* __restrict__ topi,
                                                     float* __restrict__ topv,
                                                     int* __restrict__ counts) {
  __shared__ float gsh[NE * HD];  // 64 KiB
  const int tid = threadIdx.x;
  const int wave = tid >> 6;
  const int lane = tid & 63;
  const int t = blockIdx.x * 4 + wave;

  // stage gw: 256 threads x 16 fv4 = 64 KiB, coalesced
#pragma unroll
  for (int r = 0; r < 16; ++r) {
    int idx = r * 256 + tid;
    ((fv4*)gsh)[idx] = ((const fv4*)gw)[idx];
  }

  // x row register-resident: lane holds h = q*256 + lane*4 .. +3
  const float* xr = x + (size_t)t * HD;
  fv4 xa[4];
#pragma unroll
  for (int q = 0; q < 4; ++q) xa[q] = *(const fv4*)(xr + q * 256 + lane * 4);

  __syncthreads();

  float p[NE];
#pragma unroll
  for (int e = 0; e < NE; ++e) {
    const float* g = gsh + e * HD;
    float a = 0.f;
#pragma unroll
    for (int q = 0; q < 4; ++q) {
      fv4 gv = *(const fv4*)(g + q * 256 + lane * 4);
      a += xa[q][0] * gv[0] + xa[q][1] * gv[1] + xa[q][2] * gv[2] + xa[q][3] * gv[3];
    }
    p[e] = a;
  }
  // batched butterfly reduction across 64 lanes for all 16 experts
#pragma unroll
  for (int off = 1; off < 64; off <<= 1) {
#pragma unroll
    for (int e = 0; e < NE; ++e) p[e] += __shfl_xor(p[e], off);
  }

  // branchless top-4 selection, all lanes, pure registers (no scratch)
  int sel_i[4]; float sel_v[4];
#pragma unroll
  for (int k = 0; k < 4; ++k) {
    float best = p[0]; int bi = 0;
#pragma unroll
    for (int e = 1; e < NE; ++e) {
      bool c = p[e] > best;
      best = c ? p[e] : best;
      bi   = c ? e : bi;
    }
    sel_i[k] = bi; sel_v[k] = best;
#pragma unroll
    for (int e = 0; e < NE; ++e) p[e] = (e == bi) ? -3.4e38f : p[e];
  }
  float m = sel_v[0];
  float e0 = expf(sel_v[0] - m), e1 = expf(sel_v[1] - m);
  float e2 = expf(sel_v[2] - m), e3 = expf(sel_v[3] - m);
  float inv = 1.f / (e0 + e1 + e2 + e3);

  if (lane == 0) {
    topi[t * 4 + 0] = sel_i[0]; topv[t * 4 + 0] = e0 * inv;
    topi[t * 4 + 1] = sel_i[1]; topv[t * 4 + 1] = e1 * inv;
    topi[t * 4 + 2] = sel_i[2]; topv[t * 4 + 2] = e2 * inv;
    topi[t * 4 + 3] = sel_i[3]; topv[t * 4 + 3] = e3 * inv;
    atomicAdd(&counts[sel_i[0]], 1);
    atomicAdd(&counts[sel_i[1]], 1);
    atomicAdd(&counts[sel_i[2]], 1);
    atomicAdd(&counts[sel_i[3]], 1);
  }
}

// ---------- scan counts -> offsets ----------
__global__ void scan_kernel(const int* __restrict__ counts, int* __restrict__ offsets) {
  if (threadIdx.x == 0 && blockIdx.x == 0) {
    int acc = 0;
    for (int e = 0; e < NE; ++e) { offsets[e] = acc; acc += counts[e]; }
    offsets[NE] = acc;
  }
}

// ---------- assign pair slots ----------
__global__ __launch_bounds__(256) void assign_kernel(const int* __restrict__ topi,
                                                     const int* __restrict__ offsets,
                                                     int* __restrict__ fill,
                                                     int* __restrict__ pair_token,
                                                     int* __restrict__ pair_slot) {
  int p = blockIdx.x * 256 + threadIdx.x;     // 8192
  if (p >= NPAIR) return;
  int t = p >> 2;
  int e = topi[p];
  int pos = atomicAdd(&fill[e], 1);
  int slot = offsets[e] + pos;
  pair_token[slot] = t;
  pair_slot[p] = slot;
}

// ---------- templated GEMM: C[M,N] = A_bf16[M,K] @ B_f32[N,K]^T ----------
// MODE 0: GU    A=x_bf16 M=2048, B=shared_gu N=2048 -> gu f32 (stride 2048)
// MODE 1: DOWN  A=act    M=2048, B=shared_down N=1024 -> d_out f32
// MODE 2: H1    A=x_bf16 gathered by pair_token, B=w1[e] -> silu -> h1 bf16
// MODE 3: YP    A=h1 rows=slots, B=w2[e] -> y f32
template <int MODE>
__global__ __launch_bounds__(256) void gemm_kernel(const bf16* __restrict__ Abase,
                                                   const float* __restrict__ Bbase,
                                                   void* __restrict__ OutBase,
                                                   const int* __restrict__ pair_token,
                                                   const int* __restrict__ offsets) {
  constexpr int NCOLS = (MODE == 0) ? 2048 : 1024;
  constexpr int NT = NCOLS / 128;

  __shared__ bf16 Ash[128][32];
  __shared__ bf16 Bsh[128][32];

  const int tid = threadIdx.x;
  const int lane = tid & 63;
  const int wave = tid >> 6;
  const int wm = wave >> 1, wn = wave & 1;

  int mt, nt, seg_start = 0, count = 0;
  size_t ebase = 0;
  if (MODE == 0 || MODE == 1) {
    mt = blockIdx.x / NT; nt = blockIdx.x % NT;
  } else {
    int e = blockIdx.x / (16 * NT);
    int r = blockIdx.x % (16 * NT);
    mt = r / NT; nt = r % NT;
    seg_start = offsets[e];
    count = offsets[e + 1] - seg_start;
    if (mt * 128 >= count) return;
    ebase = (size_t)e * 1024 * 1024;
  }

  // Precompute per-lane A row base pointers for the two staging rounds
  const bf16* arow[2];
#pragma unroll
  for (int r = 0; r < 2; ++r) {
    int rowloc = r * 64 + wave * 16 + (lane >> 2);
    int grow;
    if (MODE == 0 || MODE == 1) {
      grow = mt * 128 + rowloc;
    } else {
      int slot = seg_start + mt * 128 + rowloc;
      if (slot > NPAIR - 1) slot = NPAIR - 1;
      grow = (MODE == 2) ? pair_token[slot] : slot;
    }
    arow[r] = Abase + (size_t)grow * KD + (lane & 3) * 8;
  }

  const float* Bexp = Bbase + ebase + (size_t)(nt * 128) * KD;

  f4acc acc[4][4];
#pragma unroll
  for (int i = 0; i < 4; ++i)
#pragma unroll
    for (int j = 0; j < 4; ++j) acc[i][j] = (f4acc)(0.f);

  for (int kt = 0; kt < KD / 32; ++kt) {
    const int k0 = kt * 32;
    // stage A tile via global_load_lds (each wave: 16 rows per round)
#pragma unroll
    for (int r = 0; r < 2; ++r) {
      async16(arow[r] + k0, (void*)&Ash[r * 64 + wave * 16][0]);
    }
    // stage B tile: fp32 -> bf16 reg-staged
#pragma unroll
    for (int r = 0; r < 4; ++r) {
      int idx = (r << 8) + tid;
      int row = idx >> 3, cg = idx & 7;
      fv4 v = *(const fv4*)(Bexp + (size_t)row * KD + k0 + (cg << 2));
      sh4 pk; pk[0]=f2bf(v[0]); pk[1]=f2bf(v[1]); pk[2]=f2bf(v[2]); pk[3]=f2bf(v[3]);
      *(sh4*)&Bsh[row][cg << 2] = pk;
    }
    __syncthreads();

    sh8 fa[4], fb[4];
#pragma unroll
    for (int mi = 0; mi < 4; ++mi)
      fa[mi] = *(const sh8*)&Ash[wm * 64 + mi * 16 + (lane & 15)][(lane >> 4) * 8];
#pragma unroll
    for (int ni = 0; ni < 4; ++ni)
      fb[ni] = *(const sh8*)&Bsh[wn * 64 + ni * 16 + (lane & 15)][(lane >> 4) * 8];
#pragma unroll
    for (int mi = 0; mi < 4; ++mi)
#pragma unroll
      for (int ni = 0; ni < 4; ++ni)
        acc[mi][ni] = __builtin_amdgcn_mfma_f32_16x16x32_bf16(fa[mi], fb[ni], acc[mi][ni], 0, 0, 0);
    __syncthreads();
  }

  // epilogue: C/D layout col = lane&15, row = (lane>>4)*4 + j
#pragma unroll
  for (int mi = 0; mi < 4; ++mi) {
#pragma unroll
    for (int ni = 0; ni < 4; ++ni) {
#pragma unroll
      for (int j = 0; j < 4; ++j) {
        int rloc = wm * 64 + mi * 16 + (lane >> 4) * 4 + j;
        int cloc = wn * 64 + ni * 16 + (lane & 15);
        float v = acc[mi][ni][j];
        if (MODE == 0) {
          ((float*)OutBase)[(size_t)(mt * 128 + rloc) * 2048 + nt * 128 + cloc] = v;
        } else if (MODE == 1) {
          ((float*)OutBase)[(size_t)(mt * 128 + rloc) * 1024 + nt * 128 + cloc] = v;
        } else if (MODE == 2) {
          if (mt * 128 + rloc < count) {
            float s = v / (1.f + expf(-v));
            ((short*)OutBase)[(size_t)(seg_start + mt * 128 + rloc) * 1024 + nt * 128 + cloc] = f2bf(s);
          }
        } else {
          if (mt * 128 + rloc < count)
            ((float*)OutBase)[(size_t)(seg_start + mt * 128 + rloc) * 1024 + nt * 128 + cloc] = v;
        }
      }
    }
  }
}

// ---------- shared-expert activation: act = silu(gate) * up ----------
__global__ __launch_bounds__(256) void act_kernel(const float* __restrict__ gu,
                                                  bf16* __restrict__ act) {
  int i = blockIdx.x * 256 + threadIdx.x;  // 2048*256; 4 elems each
  int t = i >> 8, g = i & 255;
  fv4 gate = *(const fv4*)(gu + (size_t)t * 2048 + g * 4);
  fv4 up   = *(const fv4*)(gu + (size_t)t * 2048 + 1024 + g * 4);
  sh4 o;
#pragma unroll
  for (int q = 0; q < 4; ++q) {
    float gg = gate[q];
    float s = gg / (1.f + expf(-gg)) * up[q];
    o[q] = f2bf(s);
  }
  *(sh4*)((short*)act + (size_t)t * 1024 + g * 4) = o;
}

// ---------- final: out += sum_k w_k * y[slot_k] ----------
__global__ __launch_bounds__(256) void reduce_kernel(float* __restrict__ out,
                                                     const float* __restrict__ y,
                                                     const int* __restrict__ pslot,
                                                     const float* __restrict__ topv) {
  int t = blockIdx.x;
  int q = threadIdx.x;  // 256 float4 per row
  int s0 = pslot[t * 4 + 0], s1 = pslot[t * 4 + 1];
  int s2 = pslot[t * 4 + 2], s3 = pslot[t * 4 + 3];
  float w0 = topv[t * 4 + 0], w1 = topv[t * 4 + 1];
  float w2 = topv[t * 4 + 2], w3 = topv[t * 4 + 3];
  fv4 o = ((const fv4*)(out + (size_t)t * 1024))[q];
  o += w0 * ((const fv4*)(y + (size_t)s0 * 1024))[q];
  o += w1 * ((const fv4*)(y + (size_t)s1 * 1024))[q];
  o += w2 * ((const fv4*)(y + (size_t)s2 * 1024))[q];
  o += w3 * ((const fv4*)(y + (size_t)s3 * 1024))[q];
  ((fv4*)(out + (size_t)t * 1024))[q] = o;
}

extern "C" void kernel_launch(void* const* d_in, const int* in_sizes, int n_in,
                              void* d_out, int out_size, void* d_ws, size_t ws_size,
                              hipStream_t stream) {
  const float* x   = (const float*)d_in[0];
  const float* gw  = (const float*)d_in[1];
  const float* w1  = (const float*)d_in[2];
  const float* w2  = (const float*)d_in[3];
  const float* sgu = (const float*)d_in[4];
  const float* sdn = (const float*)d_in[5];
  float* out = (float*)d_out;

  char* ws = (char*)d_ws;
  bf16*  xb    = (bf16*)(ws + OFF_XB);
  float* gu    = (float*)(ws + OFF_GU);
  bf16*  act   = (bf16*)(ws + OFF_ACT);
  bf16*  h1    = (bf16*)(ws + OFF_H1);
  float* yb    = (float*)(ws + OFF_Y);
  int*   topi  = (int*)(ws + OFF_TOPI);
  float* topv  = (float*)(ws + OFF_TOPV);
  int*   ptok  = (int*)(ws + OFF_PTOK);
  int*   pslot = (int*)(ws + OFF_PSLOT);
  int*   cnt   = (int*)(ws + OFF_CNT);
  int*   fill  = (int*)(ws + OFF_FILL);
  int*   offs  = (int*)(ws + OFF_OFFS);

  hipMemsetAsync(ws + OFF_CNT, 0, 512, stream);  // counts + fill

  cast_x_kernel<<<2048, 256, 0, stream>>>(x, xb);
  router_kernel<<<512, 256, 0, stream>>>(x, gw, topi, topv, cnt);
  scan_kernel<<<1, 64, 0, stream>>>(cnt, offs);
  assign_kernel<<<32, 256, 0, stream>>>(topi, offs, fill, ptok, pslot);

  // shared expert
  gemm_kernel<0><<<16 * 16, 256, 0, stream>>>(xb, sgu, gu, nullptr, nullptr);
  act_kernel<<<2048, 256, 0, stream>>>(gu, act);
  gemm_kernel<1><<<16 * 8, 256, 0, stream>>>(act, sdn, out, nullptr, nullptr);

  // routed experts
  gemm_kernel<2><<<16 * 16 * 8, 256, 0, stream>>>(xb, w1, h1, ptok, offs);
  gemm_kernel<3><<<16 * 16 * 8, 256, 0, stream>>>(h1, w2, yb, ptok, offs);

  reduce_kernel<<<2048, 256, 0, stream>>>(out, yb, pslot, topv);
}

// Round 4
// 206.617 us; speedup vs baseline: 1.7753x; 1.4776x over previous
//
#include <hip/hip_runtime.h>
#include <hip/hip_bf16.h>
#include <math.h>

using bf16 = __hip_bfloat16;

typedef __attribute__((ext_vector_type(4))) float fv4;
typedef __attribute__((ext_vector_type(4))) short sh4;
typedef __attribute__((ext_vector_type(8))) short sh8;
typedef __attribute__((ext_vector_type(4))) float f4acc;

#define T_TOK 2048
#define HD    1024
#define NE    16
#define KD    1024
#define NPAIR 8192

// ---- workspace layout (bytes) ----
static constexpr size_t OFF_XB    = 0;                       // bf16 x  [2048][1024]   4 MiB
static constexpr size_t OFF_GU    = 4194304;                 // f32 gu  [2048][2048]  16 MiB
static constexpr size_t OFF_ACT   = 20971520;                // bf16 act[2048][1024]   4 MiB
static constexpr size_t OFF_H1    = 25165824;                // bf16 h1 [8192][1024]  16 MiB
static constexpr size_t OFF_Y     = 41943040;                // f32 y   [8192][1024]  32 MiB
static constexpr size_t OFF_TOPI  = 75497472;                // int  [2048*4]
static constexpr size_t OFF_TOPV  = 75530240;                // f32  [2048*4]
static constexpr size_t OFF_PTOK  = 75563008;                // int  [8192]
static constexpr size_t OFF_PSLOT = 75595776;                // int  [8192]
static constexpr size_t OFF_OFFS  = 75629056;                // int  [17]

__device__ __forceinline__ short f2bf(float f) {
  __hip_bfloat16 h = __float2bfloat16(f);
  union { __hip_bfloat16 b; short s; } u; u.b = h; return u.s;
}
__device__ __forceinline__ void async16(const void* g, void* l) {
  __builtin_amdgcn_global_load_lds(
      (const __attribute__((address_space(1))) void*)g,
      (__attribute__((address_space(3))) void*)l, 16, 0, 0);
}

// ---------- cast x (fp32 -> bf16) ----------
__global__ __launch_bounds__(256) void cast_x_kernel(const float* __restrict__ x,
                                                     bf16* __restrict__ xb) {
  int i = blockIdx.x * 256 + threadIdx.x;      // one float4 per thread; 524288 total
  fv4 v = *(const fv4*)(x + (size_t)i * 4);
  sh4 o; o[0]=f2bf(v[0]); o[1]=f2bf(v[1]); o[2]=f2bf(v[2]); o[3]=f2bf(v[3]);
  *(sh4*)((short*)xb + (size_t)i * 4) = o;
}

// ---------- router v4: NO atomics; gw in LDS, branchless register top-4 ----------
__global__ __launch_bounds__(256) void router_kernel(const float* __restrict__ x,
                                                     const float* __restrict__ gw,
                                                     int* __restrict__ topi,
                                                     float* __restrict__ topv) {
  __shared__ float gsh[NE * HD];  // 64 KiB
  const int tid = threadIdx.x;
  const int wave = tid >> 6;
  const int lane = tid & 63;
  const int t = blockIdx.x * 4 + wave;

  // stage gw: 256 threads x 16 fv4 = 64 KiB, coalesced
#pragma unroll
  for (int r = 0; r < 16; ++r) {
    int idx = r * 256 + tid;
    ((fv4*)gsh)[idx] = ((const fv4*)gw)[idx];
  }

  // x row register-resident: lane holds h = q*256 + lane*4 .. +3
  const float* xr = x + (size_t)t * HD;
  fv4 xa[4];
#pragma unroll
  for (int q = 0; q < 4; ++q) xa[q] = *(const fv4*)(xr + q * 256 + lane * 4);

  __syncthreads();

  float p[NE];
#pragma unroll
  for (int e = 0; e < NE; ++e) {
    const float* g = gsh + e * HD;
    float a = 0.f;
#pragma unroll
    for (int q = 0; q < 4; ++q) {
      fv4 gv = *(const fv4*)(g + q * 256 + lane * 4);
      a += xa[q][0] * gv[0] + xa[q][1] * gv[1] + xa[q][2] * gv[2] + xa[q][3] * gv[3];
    }
    p[e] = a;
  }
  // batched butterfly reduction across 64 lanes for all 16 experts
#pragma unroll
  for (int off = 1; off < 64; off <<= 1) {
#pragma unroll
    for (int e = 0; e < NE; ++e) p[e] += __shfl_xor(p[e], off);
  }

  // branchless top-4 selection, all lanes, pure registers (no scratch)
  int sel_i[4]; float sel_v[4];
#pragma unroll
  for (int k = 0; k < 4; ++k) {
    float best = p[0]; int bi = 0;
#pragma unroll
    for (int e = 1; e < NE; ++e) {
      bool c = p[e] > best;
      best = c ? p[e] : best;
      bi   = c ? e : bi;
    }
    sel_i[k] = bi; sel_v[k] = best;
#pragma unroll
    for (int e = 0; e < NE; ++e) p[e] = (e == bi) ? -3.4e38f : p[e];
  }
  float m = sel_v[0];
  float e0 = expf(sel_v[0] - m), e1 = expf(sel_v[1] - m);
  float e2 = expf(sel_v[2] - m), e3 = expf(sel_v[3] - m);
  float inv = 1.f / (e0 + e1 + e2 + e3);

  if (lane == 0) {
    topi[t * 4 + 0] = sel_i[0]; topv[t * 4 + 0] = e0 * inv;
    topi[t * 4 + 1] = sel_i[1]; topv[t * 4 + 1] = e1 * inv;
    topi[t * 4 + 2] = sel_i[2]; topv[t * 4 + 2] = e2 * inv;
    topi[t * 4 + 3] = sel_i[3]; topv[t * 4 + 3] = e3 * inv;
  }
}

// ---------- route build: counts + offsets + compaction, ballot-based, no atomics ----------
// one block, 16 waves; wave e owns expert e
__global__ __launch_bounds__(1024) void route_build_kernel(const int* __restrict__ topi,
                                                           int* __restrict__ offsets,
                                                           int* __restrict__ pair_token,
                                                           int* __restrict__ pair_slot) {
  __shared__ int tsh[NPAIR];      // 32 KiB
  __shared__ int cnt_sh[NE];
  __shared__ int off_sh[NE + 1];
  const int tid = threadIdx.x;
  const int wave = tid >> 6;      // == expert id
  const int lane = tid & 63;

  // stage topi into LDS
#pragma unroll
  for (int r = 0; r < NPAIR / 1024; ++r) tsh[r * 1024 + tid] = topi[r * 1024 + tid];
  __syncthreads();

  const int e = wave;
  // pass 1: count
  int cnt = 0;
  for (int c = 0; c < NPAIR; c += 64) {
    unsigned long long msk = __ballot(tsh[c + lane] == e);
    cnt += __popcll(msk);
  }
  if (lane == 0) cnt_sh[e] = cnt;
  __syncthreads();
  if (tid == 0) {
    int acc = 0;
    for (int i = 0; i < NE; ++i) { off_sh[i] = acc; acc += cnt_sh[i]; }
    off_sh[NE] = acc;
  }
  __syncthreads();
  if (tid <= NE) offsets[tid] = off_sh[tid];

  // pass 2: compact (deterministic: pair order within expert = p order)
  int base = off_sh[e];
  for (int c = 0; c < NPAIR; c += 64) {
    bool match = (tsh[c + lane] == e);
    unsigned long long msk = __ballot(match);
    unsigned long long lt = (lane == 0) ? 0ull : ((~0ull) >> (64 - lane));
    int pre = __popcll(msk & lt);
    if (match) {
      int slot = base + pre;
      pair_token[slot] = (c + lane) >> 2;
      pair_slot[c + lane] = slot;
    }
    base += __popcll(msk);
  }
}

// ---------- templated GEMM: C[M,N] = A_bf16[M,K] @ B_f32[N,K]^T ----------
// MODE 0: GU    A=x_bf16 M=2048, B=shared_gu N=2048 -> gu f32 (stride 2048)
// MODE 1: DOWN  A=act    M=2048, B=shared_down N=1024 -> d_out f32
// MODE 2: H1    A=x_bf16 gathered by pair_token, B=w1[e] -> silu -> h1 bf16
// MODE 3: YP    A=h1 rows=slots, B=w2[e] -> y f32
template <int MODE>
__global__ __launch_bounds__(256) void gemm_kernel(const bf16* __restrict__ Abase,
                                                   const float* __restrict__ Bbase,
                                                   void* __restrict__ OutBase,
                                                   const int* __restrict__ pair_token,
                                                   const int* __restrict__ offsets) {
  constexpr int NCOLS = (MODE == 0) ? 2048 : 1024;
  constexpr int NT = NCOLS / 128;

  __shared__ bf16 Ash[128][32];
  __shared__ bf16 Bsh[128][32];

  const int tid = threadIdx.x;
  const int lane = tid & 63;
  const int wave = tid >> 6;
  const int wm = wave >> 1, wn = wave & 1;

  int mt, nt, seg_start = 0, count = 0;
  size_t ebase = 0;
  if (MODE == 0 || MODE == 1) {
    mt = blockIdx.x / NT; nt = blockIdx.x % NT;
  } else {
    int e = blockIdx.x / (16 * NT);
    int r = blockIdx.x % (16 * NT);
    mt = r / NT; nt = r % NT;
    seg_start = offsets[e];
    count = offsets[e + 1] - seg_start;
    if (mt * 128 >= count) return;
    ebase = (size_t)e * 1024 * 1024;
  }

  // Precompute per-lane A row base pointers for the two staging rounds
  const bf16* arow[2];
#pragma unroll
  for (int r = 0; r < 2; ++r) {
    int rowloc = r * 64 + wave * 16 + (lane >> 2);
    int grow;
    if (MODE == 0 || MODE == 1) {
      grow = mt * 128 + rowloc;
    } else {
      int slot = seg_start + mt * 128 + rowloc;
      if (slot > NPAIR - 1) slot = NPAIR - 1;
      grow = (MODE == 2) ? pair_token[slot] : slot;
    }
    arow[r] = Abase + (size_t)grow * KD + (lane & 3) * 8;
  }

  const float* Bexp = Bbase + ebase + (size_t)(nt * 128) * KD;

  f4acc acc[4][4];
#pragma unroll
  for (int i = 0; i < 4; ++i)
#pragma unroll
    for (int j = 0; j < 4; ++j) acc[i][j] = (f4acc)(0.f);

  for (int kt = 0; kt < KD / 32; ++kt) {
    const int k0 = kt * 32;
    // stage A tile via global_load_lds (each wave: 16 rows per round)
#pragma unroll
    for (int r = 0; r < 2; ++r) {
      async16(arow[r] + k0, (void*)&Ash[r * 64 + wave * 16][0]);
    }
    // stage B tile: fp32 -> bf16 reg-staged
#pragma unroll
    for (int r = 0; r < 4; ++r) {
      int idx = (r << 8) + tid;
      int row = idx >> 3, cg = idx & 7;
      fv4 v = *(const fv4*)(Bexp + (size_t)row * KD + k0 + (cg << 2));
      sh4 pk; pk[0]=f2bf(v[0]); pk[1]=f2bf(v[1]); pk[2]=f2bf(v[2]); pk[3]=f2bf(v[3]);
      *(sh4*)&Bsh[row][cg << 2] = pk;
    }
    __syncthreads();

    sh8 fa[4], fb[4];
#pragma unroll
    for (int mi = 0; mi < 4; ++mi)
      fa[mi] = *(const sh8*)&Ash[wm * 64 + mi * 16 + (lane & 15)][(lane >> 4) * 8];
#pragma unroll
    for (int ni = 0; ni < 4; ++ni)
      fb[ni] = *(const sh8*)&Bsh[wn * 64 + ni * 16 + (lane & 15)][(lane >> 4) * 8];
#pragma unroll
    for (int mi = 0; mi < 4; ++mi)
#pragma unroll
      for (int ni = 0; ni < 4; ++ni)
        acc[mi][ni] = __builtin_amdgcn_mfma_f32_16x16x32_bf16(fa[mi], fb[ni], acc[mi][ni], 0, 0, 0);
    __syncthreads();
  }

  // epilogue: C/D layout col = lane&15, row = (lane>>4)*4 + j
#pragma unroll
  for (int mi = 0; mi < 4; ++mi) {
#pragma unroll
    for (int ni = 0; ni < 4; ++ni) {
#pragma unroll
      for (int j = 0; j < 4; ++j) {
        int rloc = wm * 64 + mi * 16 + (lane >> 4) * 4 + j;
        int cloc = wn * 64 + ni * 16 + (lane & 15);
        float v = acc[mi][ni][j];
        if (MODE == 0) {
          ((float*)OutBase)[(size_t)(mt * 128 + rloc) * 2048 + nt * 128 + cloc] = v;
        } else if (MODE == 1) {
          ((float*)OutBase)[(size_t)(mt * 128 + rloc) * 1024 + nt * 128 + cloc] = v;
        } else if (MODE == 2) {
          if (mt * 128 + rloc < count) {
            float s = v / (1.f + expf(-v));
            ((short*)OutBase)[(size_t)(seg_start + mt * 128 + rloc) * 1024 + nt * 128 + cloc] = f2bf(s);
          }
        } else {
          if (mt * 128 + rloc < count)
            ((float*)OutBase)[(size_t)(seg_start + mt * 128 + rloc) * 1024 + nt * 128 + cloc] = v;
        }
      }
    }
  }
}

// ---------- shared-expert activation: act = silu(gate) * up ----------
__global__ __launch_bounds__(256) void act_kernel(const float* __restrict__ gu,
                                                  bf16* __restrict__ act) {
  int i = blockIdx.x * 256 + threadIdx.x;  // 2048*256; 4 elems each
  int t = i >> 8, g = i & 255;
  fv4 gate = *(const fv4*)(gu + (size_t)t * 2048 + g * 4);
  fv4 up   = *(const fv4*)(gu + (size_t)t * 2048 + 1024 + g * 4);
  sh4 o;
#pragma unroll
  for (int q = 0; q < 4; ++q) {
    float gg = gate[q];
    float s = gg / (1.f + expf(-gg)) * up[q];
    o[q] = f2bf(s);
  }
  *(sh4*)((short*)act + (size_t)t * 1024 + g * 4) = o;
}

// ---------- final: out += sum_k w_k * y[slot_k] ----------
__global__ __launch_bounds__(256) void reduce_kernel(float* __restrict__ out,
                                                     const float* __restrict__ y,
                                                     const int* __restrict__ pslot,
                                                     const float* __restrict__ topv) {
  int t = blockIdx.x;
  int q = threadIdx.x;  // 256 float4 per row
  int s0 = pslot[t * 4 + 0], s1 = pslot[t * 4 + 1];
  int s2 = pslot[t * 4 + 2], s3 = pslot[t * 4 + 3];
  float w0 = topv[t * 4 + 0], w1 = topv[t * 4 + 1];
  float w2 = topv[t * 4 + 2], w3 = topv[t * 4 + 3];
  fv4 o = ((const fv4*)(out + (size_t)t * 1024))[q];
  o += w0 * ((const fv4*)(y + (size_t)s0 * 1024))[q];
  o += w1 * ((const fv4*)(y + (size_t)s1 * 1024))[q];
  o += w2 * ((const fv4*)(y + (size_t)s2 * 1024))[q];
  o += w3 * ((const fv4*)(y + (size_t)s3 * 1024))[q];
  ((fv4*)(out + (size_t)t * 1024))[q] = o;
}

extern "C" void kernel_launch(void* const* d_in, const int* in_sizes, int n_in,
                              void* d_out, int out_size, void* d_ws, size_t ws_size,
                              hipStream_t stream) {
  const float* x   = (const float*)d_in[0];
  const float* gw  = (const float*)d_in[1];
  const float* w1  = (const float*)d_in[2];
  const float* w2  = (const float*)d_in[3];
  const float* sgu = (const float*)d_in[4];
  const float* sdn = (const float*)d_in[5];
  float* out = (float*)d_out;

  char* ws = (char*)d_ws;
  bf16*  xb    = (bf16*)(ws + OFF_XB);
  float* gu    = (float*)(ws + OFF_GU);
  bf16*  act   = (bf16*)(ws + OFF_ACT);
  bf16*  h1    = (bf16*)(ws + OFF_H1);
  float* yb    = (float*)(ws + OFF_Y);
  int*   topi  = (int*)(ws + OFF_TOPI);
  float* topv  = (float*)(ws + OFF_TOPV);
  int*   ptok  = (int*)(ws + OFF_PTOK);
  int*   pslot = (int*)(ws + OFF_PSLOT);
  int*   offs  = (int*)(ws + OFF_OFFS);

  cast_x_kernel<<<2048, 256, 0, stream>>>(x, xb);
  router_kernel<<<512, 256, 0, stream>>>(x, gw, topi, topv);
  route_build_kernel<<<1, 1024, 0, stream>>>(topi, offs, ptok, pslot);

  // shared expert
  gemm_kernel<0><<<16 * 16, 256, 0, stream>>>(xb, sgu, gu, nullptr, nullptr);
  act_kernel<<<2048, 256, 0, stream>>>(gu, act);
  gemm_kernel<1><<<16 * 8, 256, 0, stream>>>(act, sdn, out, nullptr, nullptr);

  // routed experts
  gemm_kernel<2><<<16 * 16 * 8, 256, 0, stream>>>(xb, w1, h1, ptok, offs);
  gemm_kernel<3><<<16 * 16 * 8, 256, 0, stream>>>(h1, w2, yb, ptok, offs);

  reduce_kernel<<<2048, 256, 0, stream>>>(out, yb, pslot, topv);
}

// Round 5
// 190.905 us; speedup vs baseline: 1.9214x; 1.0823x over previous
//
#include <hip/hip_runtime.h>
#include <hip/hip_bf16.h>
#include <math.h>

using bf16 = __hip_bfloat16;

typedef __attribute__((ext_vector_type(4))) float fv4;
typedef __attribute__((ext_vector_type(4))) short sh4;
typedef __attribute__((ext_vector_type(8))) short sh8;
typedef __attribute__((ext_vector_type(4))) float f4acc;

#define T_TOK 2048
#define HD    1024
#define NE    16
#define KD    1024
#define NPAIR 8192

// ---- workspace layout (bytes) ----
static constexpr size_t OFF_XB    = 0;                       // bf16 x  [2048][1024]   4 MiB
static constexpr size_t OFF_GU    = 4194304;                 // f32 gu  [2048][2048]  16 MiB
static constexpr size_t OFF_ACT   = 20971520;                // bf16 act[2048][1024]   4 MiB
static constexpr size_t OFF_H1    = 25165824;                // bf16 h1 [8192][1024]  16 MiB
static constexpr size_t OFF_Y     = 41943040;                // f32 y   [8192][1024]  32 MiB
static constexpr size_t OFF_TOPI  = 75497472;                // int  [2048*4]
static constexpr size_t OFF_TOPV  = 75530240;                // f32  [2048*4]
static constexpr size_t OFF_PTOK  = 75563008;                // int  [8192]
static constexpr size_t OFF_PSLOT = 75595776;                // int  [8192]
static constexpr size_t OFF_OFFS  = 75629056;                // int  [17]

__device__ __forceinline__ short f2bf(float f) {
  __hip_bfloat16 h = __float2bfloat16(f);
  union { __hip_bfloat16 b; short s; } u; u.b = h; return u.s;
}
__device__ __forceinline__ void async16(const void* g, void* l) {
  __builtin_amdgcn_global_load_lds(
      (const __attribute__((address_space(1))) void*)g,
      (__attribute__((address_space(3))) void*)l, 16, 0, 0);
}

// ---------- cast x (fp32 -> bf16) ----------
__global__ __launch_bounds__(256) void cast_x_kernel(const float* __restrict__ x,
                                                     bf16* __restrict__ xb) {
  int i = blockIdx.x * 256 + threadIdx.x;      // one float4 per thread; 524288 total
  fv4 v = *(const fv4*)(x + (size_t)i * 4);
  sh4 o; o[0]=f2bf(v[0]); o[1]=f2bf(v[1]); o[2]=f2bf(v[2]); o[3]=f2bf(v[3]);
  *(sh4*)((short*)xb + (size_t)i * 4) = o;
}

// ---------- router: NO atomics; gw in LDS, branchless register top-4 ----------
__global__ __launch_bounds__(256) void router_kernel(const float* __restrict__ x,
                                                     const float* __restrict__ gw,
                                                     int* __restrict__ topi,
                                                     float* __restrict__ topv) {
  __shared__ float gsh[NE * HD];  // 64 KiB
  const int tid = threadIdx.x;
  const int wave = tid >> 6;
  const int lane = tid & 63;
  const int t = blockIdx.x * 4 + wave;

#pragma unroll
  for (int r = 0; r < 16; ++r) {
    int idx = r * 256 + tid;
    ((fv4*)gsh)[idx] = ((const fv4*)gw)[idx];
  }

  const float* xr = x + (size_t)t * HD;
  fv4 xa[4];
#pragma unroll
  for (int q = 0; q < 4; ++q) xa[q] = *(const fv4*)(xr + q * 256 + lane * 4);

  __syncthreads();

  float p[NE];
#pragma unroll
  for (int e = 0; e < NE; ++e) {
    const float* g = gsh + e * HD;
    float a = 0.f;
#pragma unroll
    for (int q = 0; q < 4; ++q) {
      fv4 gv = *(const fv4*)(g + q * 256 + lane * 4);
      a += xa[q][0] * gv[0] + xa[q][1] * gv[1] + xa[q][2] * gv[2] + xa[q][3] * gv[3];
    }
    p[e] = a;
  }
#pragma unroll
  for (int off = 1; off < 64; off <<= 1) {
#pragma unroll
    for (int e = 0; e < NE; ++e) p[e] += __shfl_xor(p[e], off);
  }

  int sel_i[4]; float sel_v[4];
#pragma unroll
  for (int k = 0; k < 4; ++k) {
    float best = p[0]; int bi = 0;
#pragma unroll
    for (int e = 1; e < NE; ++e) {
      bool c = p[e] > best;
      best = c ? p[e] : best;
      bi   = c ? e : bi;
    }
    sel_i[k] = bi; sel_v[k] = best;
#pragma unroll
    for (int e = 0; e < NE; ++e) p[e] = (e == bi) ? -3.4e38f : p[e];
  }
  float m = sel_v[0];
  float e0 = expf(sel_v[0] - m), e1 = expf(sel_v[1] - m);
  float e2 = expf(sel_v[2] - m), e3 = expf(sel_v[3] - m);
  float inv = 1.f / (e0 + e1 + e2 + e3);

  if (lane == 0) {
    topi[t * 4 + 0] = sel_i[0]; topv[t * 4 + 0] = e0 * inv;
    topi[t * 4 + 1] = sel_i[1]; topv[t * 4 + 1] = e1 * inv;
    topi[t * 4 + 2] = sel_i[2]; topv[t * 4 + 2] = e2 * inv;
    topi[t * 4 + 3] = sel_i[3]; topv[t * 4 + 3] = e3 * inv;
  }
}

// ---------- route build: ballot-based, no atomics; one block, 16 waves ----------
__global__ __launch_bounds__(1024) void route_build_kernel(const int* __restrict__ topi,
                                                           int* __restrict__ offsets,
                                                           int* __restrict__ pair_token,
                                                           int* __restrict__ pair_slot) {
  __shared__ int tsh[NPAIR];
  __shared__ int cnt_sh[NE];
  __shared__ int off_sh[NE + 1];
  const int tid = threadIdx.x;
  const int wave = tid >> 6;
  const int lane = tid & 63;

#pragma unroll
  for (int r = 0; r < NPAIR / 1024; ++r) tsh[r * 1024 + tid] = topi[r * 1024 + tid];
  __syncthreads();

  const int e = wave;
  int cnt = 0;
  for (int c = 0; c < NPAIR; c += 64) {
    unsigned long long msk = __ballot(tsh[c + lane] == e);
    cnt += __popcll(msk);
  }
  if (lane == 0) cnt_sh[e] = cnt;
  __syncthreads();
  if (tid == 0) {
    int acc = 0;
    for (int i = 0; i < NE; ++i) { off_sh[i] = acc; acc += cnt_sh[i]; }
    off_sh[NE] = acc;
  }
  __syncthreads();
  if (tid <= NE) offsets[tid] = off_sh[tid];

  int base = off_sh[e];
  for (int c = 0; c < NPAIR; c += 64) {
    bool match = (tsh[c + lane] == e);
    unsigned long long msk = __ballot(match);
    unsigned long long lt = (lane == 0) ? 0ull : ((~0ull) >> (64 - lane));
    int pre = __popcll(msk & lt);
    if (match) {
      int slot = base + pre;
      pair_token[slot] = (c + lane) >> 2;
      pair_slot[c + lane] = slot;
    }
    base += __popcll(msk);
  }
}

// ---------- GEMM with 2-phase prefetch pipeline ----------
// C[M,N] = A_bf16[M,K] @ B_f32[N,K]^T ; 128x128 tile, BK=32, dbuf LDS
// MODE 0: GU    A=xb,  B=shared_gu (N=2048) -> gu f32
// MODE 1: DOWN  A=act, B=shared_down (N=1024) -> d_out f32
// MODE 2: H1    A=xb gathered, B=w1[e] -> silu -> h1 bf16
// MODE 3: YP    A=h1, B=w2[e] -> y f32
template <int MODE>
__global__ __launch_bounds__(256) void gemm_kernel(const bf16* __restrict__ Abase,
                                                   const float* __restrict__ Bbase,
                                                   void* __restrict__ OutBase,
                                                   const int* __restrict__ pair_token,
                                                   const int* __restrict__ offsets) {
  constexpr int NT = (MODE == 0) ? 16 : 8;

  __shared__ bf16 Ash[2][128][32];
  __shared__ bf16 Bsh[2][128][32];

  const int tid = threadIdx.x;
  const int lane = tid & 63;
  const int wave = tid >> 6;
  const int wm = wave >> 1, wn = wave & 1;

  int mt, nt, seg_start = 0, count = 0;
  size_t ebase = 0;
  if (MODE == 0 || MODE == 1) {
    // chunked XCD swizzle over nwg = 16*NT blocks
    constexpr int nwg = 16 * NT;
    constexpr int cpx = nwg >> 3;
    int bid = blockIdx.x;
    int sw = (bid & 7) * cpx + (bid >> 3);
    nt = sw / 16; mt = sw % 16;   // same-nt blocks contiguous within an XCD chunk
  } else {
    // expert e pinned to XCD e&7: blockIdx = (r<<4) | e
    int bid = blockIdx.x;
    int e = bid & 15;
    int r = bid >> 4;             // r in [0,128): mt = r/NT, nt = r%NT
    mt = r / NT; nt = r % NT;
    seg_start = offsets[e];
    count = offsets[e + 1] - seg_start;
    if (mt * 128 >= count) return;
    ebase = (size_t)e << 20;      // e * 1024 * 1024
  }

  // per-lane A row pointers (2 staging issues per wave: 16 rows each)
  const bf16* arow[2];
#pragma unroll
  for (int r = 0; r < 2; ++r) {
    int rowloc = r * 64 + wave * 16 + (lane >> 2);
    int grow;
    if (MODE == 0 || MODE == 1) {
      grow = mt * 128 + rowloc;
    } else {
      int slot = seg_start + mt * 128 + rowloc;
      if (slot > NPAIR - 1) slot = NPAIR - 1;
      grow = (MODE == 2) ? pair_token[slot] : slot;
    }
    arow[r] = Abase + (size_t)grow * KD + (lane & 3) * 8;
  }

  // per-thread B row pointers (4 fv4 per K-step) + LDS write rows
  const float* Bexp = Bbase + ebase + (size_t)(nt * 128) * KD;
  const float* brow[4];
  int bwrow[4], bwcol[4];
#pragma unroll
  for (int r = 0; r < 4; ++r) {
    int idx = (r << 8) + tid;
    int row = idx >> 3, cg = idx & 7;
    brow[r] = Bexp + (size_t)row * KD + (cg << 2);
    bwrow[r] = row; bwcol[r] = cg << 2;
  }

  f4acc acc[4][4];
#pragma unroll
  for (int i = 0; i < 4; ++i)
#pragma unroll
    for (int j = 0; j < 4; ++j) acc[i][j] = (f4acc)(0.f);

  // ---- prologue: stage kt=0 into buf 0 ----
  {
    fv4 b0 = *(const fv4*)(brow[0]);
    fv4 b1 = *(const fv4*)(brow[1]);
    fv4 b2 = *(const fv4*)(brow[2]);
    fv4 b3 = *(const fv4*)(brow[3]);
    async16(arow[0], (void*)&Ash[0][wave * 16][0]);
    async16(arow[1], (void*)&Ash[0][64 + wave * 16][0]);
    sh4 p0; p0[0]=f2bf(b0[0]); p0[1]=f2bf(b0[1]); p0[2]=f2bf(b0[2]); p0[3]=f2bf(b0[3]);
    sh4 p1; p1[0]=f2bf(b1[0]); p1[1]=f2bf(b1[1]); p1[2]=f2bf(b1[2]); p1[3]=f2bf(b1[3]);
    sh4 p2; p2[0]=f2bf(b2[0]); p2[1]=f2bf(b2[1]); p2[2]=f2bf(b2[2]); p2[3]=f2bf(b2[3]);
    sh4 p3; p3[0]=f2bf(b3[0]); p3[1]=f2bf(b3[1]); p3[2]=f2bf(b3[2]); p3[3]=f2bf(b3[3]);
    *(sh4*)&Bsh[0][bwrow[0]][bwcol[0]] = p0;
    *(sh4*)&Bsh[0][bwrow[1]][bwcol[1]] = p1;
    *(sh4*)&Bsh[0][bwrow[2]][bwcol[2]] = p2;
    *(sh4*)&Bsh[0][bwrow[3]][bwcol[3]] = p3;
  }
  asm volatile("s_waitcnt vmcnt(0) lgkmcnt(0)" ::: "memory");
  __builtin_amdgcn_s_barrier();

  int buf = 0;
  for (int kt = 0; kt < 32; ++kt) {
    const int k0n = (kt + 1) * 32;
    const bool has_next = (kt < 31);
    fv4 n0, n1, n2, n3;
    if (has_next) {
      // issue next-tile loads: A via async16, B into regs (overlap with MFMA below)
      async16(arow[0] + k0n, (void*)&Ash[buf ^ 1][wave * 16][0]);
      async16(arow[1] + k0n, (void*)&Ash[buf ^ 1][64 + wave * 16][0]);
      n0 = *(const fv4*)(brow[0] + k0n);
      n1 = *(const fv4*)(brow[1] + k0n);
      n2 = *(const fv4*)(brow[2] + k0n);
      n3 = *(const fv4*)(brow[3] + k0n);
    }

    // compute current tile
    sh8 fa[4], fb[4];
#pragma unroll
    for (int mi = 0; mi < 4; ++mi)
      fa[mi] = *(const sh8*)&Ash[buf][wm * 64 + mi * 16 + (lane & 15)][(lane >> 4) * 8];
#pragma unroll
    for (int ni = 0; ni < 4; ++ni)
      fb[ni] = *(const sh8*)&Bsh[buf][wn * 64 + ni * 16 + (lane & 15)][(lane >> 4) * 8];
#pragma unroll
    for (int mi = 0; mi < 4; ++mi)
#pragma unroll
      for (int ni = 0; ni < 4; ++ni)
        acc[mi][ni] = __builtin_amdgcn_mfma_f32_16x16x32_bf16(fa[mi], fb[ni], acc[mi][ni], 0, 0, 0);

    if (has_next) {
      sh4 p0; p0[0]=f2bf(n0[0]); p0[1]=f2bf(n0[1]); p0[2]=f2bf(n0[2]); p0[3]=f2bf(n0[3]);
      sh4 p1; p1[0]=f2bf(n1[0]); p1[1]=f2bf(n1[1]); p1[2]=f2bf(n1[2]); p1[3]=f2bf(n1[3]);
      sh4 p2; p2[0]=f2bf(n2[0]); p2[1]=f2bf(n2[1]); p2[2]=f2bf(n2[2]); p2[3]=f2bf(n2[3]);
      sh4 p3; p3[0]=f2bf(n3[0]); p3[1]=f2bf(n3[1]); p3[2]=f2bf(n3[2]); p3[3]=f2bf(n3[3]);
      *(sh4*)&Bsh[buf ^ 1][bwrow[0]][bwcol[0]] = p0;
      *(sh4*)&Bsh[buf ^ 1][bwrow[1]][bwcol[1]] = p1;
      *(sh4*)&Bsh[buf ^ 1][bwrow[2]][bwcol[2]] = p2;
      *(sh4*)&Bsh[buf ^ 1][bwrow[3]][bwcol[3]] = p3;
    }
    asm volatile("s_waitcnt vmcnt(0) lgkmcnt(0)" ::: "memory");
    __builtin_amdgcn_s_barrier();
    buf ^= 1;
  }

  // epilogue: C/D layout col = lane&15, row = (lane>>4)*4 + j
#pragma unroll
  for (int mi = 0; mi < 4; ++mi) {
#pragma unroll
    for (int ni = 0; ni < 4; ++ni) {
#pragma unroll
      for (int j = 0; j < 4; ++j) {
        int rloc = wm * 64 + mi * 16 + (lane >> 4) * 4 + j;
        int cloc = wn * 64 + ni * 16 + (lane & 15);
        float v = acc[mi][ni][j];
        if (MODE == 0) {
          ((float*)OutBase)[(size_t)(mt * 128 + rloc) * 2048 + nt * 128 + cloc] = v;
        } else if (MODE == 1) {
          ((float*)OutBase)[(size_t)(mt * 128 + rloc) * 1024 + nt * 128 + cloc] = v;
        } else if (MODE == 2) {
          if (mt * 128 + rloc < count) {
            float s = v / (1.f + expf(-v));
            ((short*)OutBase)[(size_t)(seg_start + mt * 128 + rloc) * 1024 + nt * 128 + cloc] = f2bf(s);
          }
        } else {
          if (mt * 128 + rloc < count)
            ((float*)OutBase)[(size_t)(seg_start + mt * 128 + rloc) * 1024 + nt * 128 + cloc] = v;
        }
      }
    }
  }
}

// ---------- shared-expert activation: act = silu(gate) * up ----------
__global__ __launch_bounds__(256) void act_kernel(const float* __restrict__ gu,
                                                  bf16* __restrict__ act) {
  int i = blockIdx.x * 256 + threadIdx.x;
  int t = i >> 8, g = i & 255;
  fv4 gate = *(const fv4*)(gu + (size_t)t * 2048 + g * 4);
  fv4 up   = *(const fv4*)(gu + (size_t)t * 2048 + 1024 + g * 4);
  sh4 o;
#pragma unroll
  for (int q = 0; q < 4; ++q) {
    float gg = gate[q];
    float s = gg / (1.f + expf(-gg)) * up[q];
    o[q] = f2bf(s);
  }
  *(sh4*)((short*)act + (size_t)t * 1024 + g * 4) = o;
}

// ---------- final: out += sum_k w_k * y[slot_k] ----------
__global__ __launch_bounds__(256) void reduce_kernel(float* __restrict__ out,
                                                     const float* __restrict__ y,
                                                     const int* __restrict__ pslot,
                                                     const float* __restrict__ topv) {
  int t = blockIdx.x;
  int q = threadIdx.x;
  int s0 = pslot[t * 4 + 0], s1 = pslot[t * 4 + 1];
  int s2 = pslot[t * 4 + 2], s3 = pslot[t * 4 + 3];
  float w0 = topv[t * 4 + 0], w1 = topv[t * 4 + 1];
  float w2 = topv[t * 4 + 2], w3 = topv[t * 4 + 3];
  fv4 o = ((const fv4*)(out + (size_t)t * 1024))[q];
  o += w0 * ((const fv4*)(y + (size_t)s0 * 1024))[q];
  o += w1 * ((const fv4*)(y + (size_t)s1 * 1024))[q];
  o += w2 * ((const fv4*)(y + (size_t)s2 * 1024))[q];
  o += w3 * ((const fv4*)(y + (size_t)s3 * 1024))[q];
  ((fv4*)(out + (size_t)t * 1024))[q] = o;
}

extern "C" void kernel_launch(void* const* d_in, const int* in_sizes, int n_in,
                              void* d_out, int out_size, void* d_ws, size_t ws_size,
                              hipStream_t stream) {
  const float* x   = (const float*)d_in[0];
  const float* gw  = (const float*)d_in[1];
  const float* w1  = (const float*)d_in[2];
  const float* w2  = (const float*)d_in[3];
  const float* sgu = (const float*)d_in[4];
  const float* sdn = (const float*)d_in[5];
  float* out = (float*)d_out;

  char* ws = (char*)d_ws;
  bf16*  xb    = (bf16*)(ws + OFF_XB);
  float* gu    = (float*)(ws + OFF_GU);
  bf16*  act   = (bf16*)(ws + OFF_ACT);
  bf16*  h1    = (bf16*)(ws + OFF_H1);
  float* yb    = (float*)(ws + OFF_Y);
  int*   topi  = (int*)(ws + OFF_TOPI);
  float* topv  = (float*)(ws + OFF_TOPV);
  int*   ptok  = (int*)(ws + OFF_PTOK);
  int*   pslot = (int*)(ws + OFF_PSLOT);
  int*   offs  = (int*)(ws + OFF_OFFS);

  cast_x_kernel<<<2048, 256, 0, stream>>>(x, xb);
  router_kernel<<<512, 256, 0, stream>>>(x, gw, topi, topv);
  route_build_kernel<<<1, 1024, 0, stream>>>(topi, offs, ptok, pslot);

  // shared expert
  gemm_kernel<0><<<256, 256, 0, stream>>>(xb, sgu, gu, nullptr, nullptr);
  act_kernel<<<2048, 256, 0, stream>>>(gu, act);
  gemm_kernel<1><<<128, 256, 0, stream>>>(act, sdn, out, nullptr, nullptr);

  // routed experts
  gemm_kernel<2><<<2048, 256, 0, stream>>>(xb, w1, h1, ptok, offs);
  gemm_kernel<3><<<2048, 256, 0, stream>>>(h1, w2, yb, ptok, offs);

  reduce_kernel<<<2048, 256, 0, stream>>>(out, yb, pslot, topv);
}